// Round 8
// baseline (293.052 us; speedup 1.0000x reference)
//
#include <hip/hip_runtime.h>

#define N_NODES 100000
#define N_EDGES 1600000
#define NCLS 40
#define NBIN ((N_NODES + 255) / 256)   // 391 scan blocks
#define SENTINEL N_NODES               // pad index -> all-zero feature row
#define NN1 (N_NODES + 1)              // rows incl. sentinel

typedef __attribute__((ext_vector_type(8))) short s8v;   // 8 bf16 (4 VGPRs)
typedef __attribute__((ext_vector_type(4))) float f4v;   // MFMA C/D
typedef __attribute__((ext_vector_type(2))) float f2v;   // packed f32 pair

__device__ __forceinline__ unsigned short f2bf(float f) {
    union { float f; unsigned int u; } v; v.f = f;
    unsigned int u = v.u + 0x7FFFu + ((v.u >> 16) & 1u);   // RNE
    return (unsigned short)(u >> 16);
}
__device__ __forceinline__ float blo(unsigned int u) {
    union { unsigned int u; float f; } v; v.u = u << 16; return v.f;
}
__device__ __forceinline__ float bhi(unsigned int u) {
    union { unsigned int u; float f; } v; v.u = u & 0xFFFF0000u; return v.f;
}

// ---------------- fp8 e4m3 encode/decode (HW builtins, soft fallback) -------
#if __has_builtin(__builtin_amdgcn_cvt_pk_fp8_f32) && __has_builtin(__builtin_amdgcn_cvt_f32_fp8)
#define FP8_HW 1
#else
#define FP8_HW 0
#endif
#if __has_builtin(__builtin_amdgcn_cvt_pk_f32_fp8)
#define FP8_PK 1
#else
#define FP8_PK 0
#endif

__device__ __forceinline__ unsigned char enc_e4m3_sw(float f) {
    union { float f; unsigned int u; } v; v.f = f;
    unsigned int s = (v.u >> 24) & 0x80u;
    float af = fabsf(f);
    if (af >= 448.0f) return (unsigned char)(s | 0x7E);
    if (af < 0.015625f) {
        int q = (int)rintf(af * 512.0f);
        return (unsigned char)(s | (q & 7));
    }
    unsigned int n = v.u & 0x7FFFFFFFu;
    n = n + 0x7FFFFu + ((n >> 20) & 1u);
    int e = (int)(n >> 23) - 120;
    unsigned int m = (n >> 20) & 7u;
    if (e <= 0) { int q = (int)rintf(af * 512.0f); return (unsigned char)(s | (q & 7)); }
    if (e > 15) return (unsigned char)(s | 0x7E);
    return (unsigned char)(s | (e << 3) | m);
}
__device__ __forceinline__ float dec_e4m3_sw(unsigned int byte) {
    unsigned int sgn = byte >> 7, e = (byte >> 3) & 15u, m = byte & 7u;
    float mag;
    if (e) { union { unsigned int u; float f; } v; v.u = ((e + 120u) << 23) | (m << 20); mag = v.f; }
    else mag = (float)m * 0.001953125f;
    return sgn ? -mag : mag;
}

__device__ __forceinline__ unsigned int pack4_fp8(float a, float b, float c, float d) {
#if FP8_HW
    unsigned int w = __builtin_amdgcn_cvt_pk_fp8_f32(a, b, 0u, false);
    w = __builtin_amdgcn_cvt_pk_fp8_f32(c, d, w, true);
    return w;
#else
    return (unsigned int)enc_e4m3_sw(a) | ((unsigned int)enc_e4m3_sw(b) << 8) |
           ((unsigned int)enc_e4m3_sw(c) << 16) | ((unsigned int)enc_e4m3_sw(d) << 24);
#endif
}

// packed accumulate: 4 fp8 of word w into two f2v accumulators (a[0],a[1])
__device__ __forceinline__ void acc_fp8pk(unsigned int w, f2v* a) {
#if FP8_PK
    a[0] += __builtin_amdgcn_cvt_pk_f32_fp8((int)w, false);   // bytes 0,1
    a[1] += __builtin_amdgcn_cvt_pk_f32_fp8((int)w, true);    // bytes 2,3
#else
    f2v lo, hi;
    lo.x = dec_e4m3_sw(w & 255u);         lo.y = dec_e4m3_sw((w >> 8) & 255u);
    hi.x = dec_e4m3_sw((w >> 16) & 255u); hi.y = dec_e4m3_sw(w >> 24);
    a[0] += lo; a[1] += hi;
#endif
}
// accumulate 16 fp8 of a uint4 into a[0..7] (f2v pairs, 16 floats total)
__device__ __forceinline__ void acc_fp8x16(uint4 u, f2v* a) {
    acc_fp8pk(u.x, a + 0); acc_fp8pk(u.y, a + 2);
    acc_fp8pk(u.z, a + 4); acc_fp8pk(u.w, a + 6);
}

// ---------------- phase 1: degree histogram + x conversions (fused) ---------
// deg[] atomics are L2-resident (400KB). xbs slice-major bf16 (k_dense root),
// xf8 64B fp8 rows (k_agg gather).
__global__ __launch_bounds__(256) void k_degxb(
        const int* __restrict__ dstv, const float* __restrict__ x,
        int* __restrict__ deg, unsigned int* __restrict__ xbs,
        unsigned int* __restrict__ h2f8, unsigned int* __restrict__ xf8) {
    int i = blockIdx.x * blockDim.x + threadIdx.x;
    int stride = gridDim.x * blockDim.x;
    for (int e = i; e < N_EDGES; e += stride) {
        int d = dstv[e]; d = min(max(d, 0), N_NODES - 1);
        atomicAdd(&deg[d], 1);
    }
    const int total = N_NODES * 8;             // 16B tiles (8 f32 -> 8 bf16)
    for (int tt = i; tt < total; tt += stride) {
        int node = tt >> 3, sub = tt & 7;      // feats sub*8 .. sub*8+7
        int slice = sub >> 1, half = sub & 1;
        float4 v0 = ((const float4*)x)[tt * 2];
        float4 v1 = ((const float4*)x)[tt * 2 + 1];
        uint4 o;
        o.x = (unsigned)f2bf(v0.x) | ((unsigned)f2bf(v0.y) << 16);
        o.y = (unsigned)f2bf(v0.z) | ((unsigned)f2bf(v0.w) << 16);
        o.z = (unsigned)f2bf(v1.x) | ((unsigned)f2bf(v1.y) << 16);
        o.w = (unsigned)f2bf(v1.z) | ((unsigned)f2bf(v1.w) << 16);
        ((uint4*)xbs)[((size_t)slice * NN1 + node) * 2 + half] = o;
        uint2 p;
        p.x = pack4_fp8(v0.x, v0.y, v0.z, v0.w);
        p.y = pack4_fp8(v1.x, v1.y, v1.z, v1.w);
        ((uint2*)xf8)[(size_t)node * 8 + sub] = p;
    }
    // zero sentinel rows: 4 xbs slices; h2 words 0..11; xf8 row (16 u32)
    uint4 z; z.x = 0u; z.y = 0u; z.z = 0u; z.w = 0u;
    if (i < 8) {
        int slice = i >> 1, half = i & 1;
        ((uint4*)xbs)[((size_t)slice * NN1 + N_NODES) * 2 + half] = z;
    }
    if (i >= 16 && i < 28) h2f8[(size_t)N_NODES * 16 + (i - 16)] = 0u;
    if (i >= 32 && i < 48) xf8[(size_t)N_NODES * 16 + (i - 32)] = 0u;
}

// ---------------- phase 2: scan padded degrees -> offdeg, cursor, pads ------
// 391 blocks x 256. Regions padded to multiples of 4 (16B-aligned int4
// blocks); pads hold SENTINEL. One atomicAdd(gcnt) per block.
__global__ __launch_bounds__(256) void k_scan(
        const int* __restrict__ deg, int* __restrict__ gcnt,
        uint2* __restrict__ offdeg, int* __restrict__ cur,
        int* __restrict__ srcs) {
    __shared__ int s[256];
    __shared__ int base_s;
    const int node = (blockIdx.x << 8) + threadIdx.x;
    int v = (node < N_NODES) ? deg[node] : 0;
    int pv = (v + 3) & ~3;                 // padded degree (multiple of 4)
    s[threadIdx.x] = pv;
    __syncthreads();
    int acc = pv;
    for (int off = 1; off < 256; off <<= 1) {
        int t = (threadIdx.x >= off) ? s[threadIdx.x - off] : 0;
        __syncthreads();
        acc += t;
        s[threadIdx.x] = acc;
        __syncthreads();
    }
    if (threadIdx.x == 255) base_s = atomicAdd(gcnt, acc);
    __syncthreads();
    const int gbeg = (acc - pv) + base_s;  // multiple of 4 -> 16B-aligned
    if (node < N_NODES) {
        offdeg[node] = make_uint2((unsigned)gbeg, (unsigned)v);
        cur[node] = gbeg;
        for (int p = v; p < pv; ++p) srcs[gbeg + p] = SENTINEL;
    }
}

// ---------------- phase 3: scatter edges into CSR ---------------------------
__global__ __launch_bounds__(256) void k_scatter(
        const int* __restrict__ srcv, const int* __restrict__ dstv,
        int* __restrict__ cur, int* __restrict__ srcs) {
    int i = blockIdx.x * blockDim.x + threadIdx.x;
    int stride = gridDim.x * blockDim.x;
    for (int e = i; e < N_EDGES; e += stride) {
        int d = dstv[e]; d = min(max(d, 0), N_NODES - 1);
        int s = srcv[e]; s = min(max(s, 0), N_NODES - 1);
        int slot = atomicAdd(&cur[d], 1);
        srcs[slot] = s;
    }
}

// ---------------- gather-mean over fp8 rows (64B = 1 line/edge) -------------
// xf8 row = 64 feats fp8 = one cache line; 4 adjacent lanes x uint4 coalesce
// to ONE line-request per edge (validated R7). Wave = 4 nodes x 4 chains x
// 4 lanes; chain walks int4 blocks with prefetch.
__global__ __launch_bounds__(256) void k_agg(
        const uint2* __restrict__ offdeg, const int* __restrict__ srcs,
        const unsigned int* __restrict__ xf8, unsigned short* __restrict__ aggs) {
    const int lane = threadIdx.x & 63;
    const int w = threadIdx.x >> 6;            // wave 0..3
    const int g = lane >> 4;                   // node subgroup 0..3
    const int c = (lane >> 2) & 3;             // chain 0..3
    const int t = lane & 3;                    // 16B quarter of 64B row
    const int wid = blockIdx.x * 4 + w;        // 0..8191
    for (int nb = wid * 4; nb < N_NODES; nb += 32768) {
        const int node = nb + g;               // N_NODES % 4 == 0 -> in range
        uint2 od = offdeg[node];
        const int beg = (int)od.x;
        const int m = ((int)od.y + 3) >> 2;
        f2v a2[8];
        #pragma unroll
        for (int k = 0; k < 8; ++k) { a2[k].x = 0.0f; a2[k].y = 0.0f; }
        int j = c;
        if (j < m) {
            int4 sv = *(const int4*)&srcs[beg + 4 * j];
            while (true) {
                const int4 cur = sv;
                const int jn = j + 4;
                if (jn < m) sv = *(const int4*)&srcs[beg + 4 * jn];   // prefetch
                uint4 u0 = *(const uint4*)&xf8[(size_t)cur.x * 16 + t * 4];
                uint4 u1 = *(const uint4*)&xf8[(size_t)cur.y * 16 + t * 4];
                uint4 u2 = *(const uint4*)&xf8[(size_t)cur.z * 16 + t * 4];
                uint4 u3 = *(const uint4*)&xf8[(size_t)cur.w * 16 + t * 4];
                acc_fp8x16(u0, a2); acc_fp8x16(u1, a2);
                acc_fp8x16(u2, a2); acc_fp8x16(u3, a2);
                if (jn >= m) break;
                j = jn;
            }
        }
        float* af = (float*)a2;
        // reduce across chains (lane bits 2,3); stays inside 16-lane node group
        #pragma unroll
        for (int k = 0; k < 16; ++k) {
            af[k] += __shfl_xor(af[k], 4, 64);
            af[k] += __shfl_xor(af[k], 8, 64);
        }
        if (c == 0) {
            // lane t holds feats 16t..16t+15 == slice t's 32B row (slice-major)
            float rd = 1.0f / fmaxf((float)od.y, 1.0f);
            uint4 r0, r1;
            r0.x = (unsigned)f2bf(af[0] * rd)  | ((unsigned)f2bf(af[1] * rd) << 16);
            r0.y = (unsigned)f2bf(af[2] * rd)  | ((unsigned)f2bf(af[3] * rd) << 16);
            r0.z = (unsigned)f2bf(af[4] * rd)  | ((unsigned)f2bf(af[5] * rd) << 16);
            r0.w = (unsigned)f2bf(af[6] * rd)  | ((unsigned)f2bf(af[7] * rd) << 16);
            r1.x = (unsigned)f2bf(af[8] * rd)  | ((unsigned)f2bf(af[9] * rd) << 16);
            r1.y = (unsigned)f2bf(af[10] * rd) | ((unsigned)f2bf(af[11] * rd) << 16);
            r1.z = (unsigned)f2bf(af[12] * rd) | ((unsigned)f2bf(af[13] * rd) << 16);
            r1.w = (unsigned)f2bf(af[14] * rd) | ((unsigned)f2bf(af[15] * rd) << 16);
            unsigned short* dst = &aggs[((size_t)t * NN1 + node) * 16];
            *(uint4*)dst = r0;
            *(uint4*)(dst + 8) = r1;
        }
    }
}

// ---------------- fused dense via MFMA; h2 fp8, 64B rows, words 0..11 -------
__global__ __launch_bounds__(256) void k_dense(
        const unsigned short* __restrict__ aggs, const unsigned short* __restrict__ xbs,
        const float* __restrict__ W1l, const float* __restrict__ b1,
        const float* __restrict__ W1r,
        const float* __restrict__ W2l, const float* __restrict__ b2,
        const float* __restrict__ W2r,
        unsigned int* __restrict__ h2f8, float* __restrict__ op) {
    __shared__ __align__(16) unsigned short wl1[64][72], wr1[64][72];
    __shared__ __align__(16) unsigned short wl2[48][72], wr2[48][72];
    __shared__ __align__(16) unsigned short hsm[4][16][72];
    for (int idx = threadIdx.x; idx < 64 * 64; idx += 256) {
        int f = idx >> 6, k = idx & 63;
        wl1[f][k] = f2bf(W1l[idx]);
        wr1[f][k] = f2bf(W1r[idx]);
    }
    for (int idx = threadIdx.x; idx < 48 * 64; idx += 256) {
        int c = idx >> 6, k = idx & 63;
        wl2[c][k] = (c < NCLS) ? f2bf(W2l[c * 64 + k]) : (unsigned short)0;
        wr2[c][k] = (c < NCLS) ? f2bf(W2r[c * 64 + k]) : (unsigned short)0;
    }
    __syncthreads();
    const int w   = threadIdx.x >> 6;
    const int l15 = threadIdx.x & 15;
    const int g   = (threadIdx.x >> 4) & 3;
    const size_t sLo = (size_t)(g >> 1) * NN1;        // feats 0..31 source
    const size_t sHi = (size_t)(2 + (g >> 1)) * NN1;  // feats 32..63 source
    const int off = (g & 1) * 8;
    float b1v[4][4], b2v[3][4];
    #pragma unroll
    for (int ft = 0; ft < 4; ++ft)
        #pragma unroll
        for (int r = 0; r < 4; ++r)
            b1v[ft][r] = b1[16 * ft + 4 * g + r];
    #pragma unroll
    for (int ct = 0; ct < 3; ++ct)
        #pragma unroll
        for (int r = 0; r < 4; ++r) {
            int c = 16 * ct + 4 * g + r;
            b2v[ct][r] = (c < NCLS) ? b2[c] : 0.0f;
        }
    unsigned short* hs = &hsm[w][0][0];
    const int gw = blockIdx.x * 4 + w;
    const int nw = gridDim.x * 4;
    for (int tile = gw; tile < N_NODES / 16; tile += nw) {
        const size_t node = (size_t)tile * 16 + l15;
        s8v aB0 = *(const s8v*)&aggs[(sLo + node) * 16 + off];
        s8v aB1 = *(const s8v*)&aggs[(sHi + node) * 16 + off];
        s8v xB0 = *(const s8v*)&xbs[(sLo + node) * 16 + off];
        s8v xB1 = *(const s8v*)&xbs[(sHi + node) * 16 + off];
        #pragma unroll
        for (int ft = 0; ft < 4; ++ft) {
            f4v c;
            c[0] = b1v[ft][0]; c[1] = b1v[ft][1]; c[2] = b1v[ft][2]; c[3] = b1v[ft][3];
            const size_t rb = (size_t)(16 * ft + l15) * 144 + 16 * g;
            s8v A0 = *(const s8v*)((const char*)wl1 + rb);
            s8v A1 = *(const s8v*)((const char*)wl1 + rb + 64);
            s8v R0 = *(const s8v*)((const char*)wr1 + rb);
            s8v R1 = *(const s8v*)((const char*)wr1 + rb + 64);
            c = __builtin_amdgcn_mfma_f32_16x16x32_bf16(A0, aB0, c, 0, 0, 0);
            c = __builtin_amdgcn_mfma_f32_16x16x32_bf16(A1, aB1, c, 0, 0, 0);
            c = __builtin_amdgcn_mfma_f32_16x16x32_bf16(R0, xB0, c, 0, 0, 0);
            c = __builtin_amdgcn_mfma_f32_16x16x32_bf16(R1, xB1, c, 0, 0, 0);
            uint2 u;
            u.x = (unsigned)f2bf(fmaxf(c[0], 0.0f)) | ((unsigned)f2bf(fmaxf(c[1], 0.0f)) << 16);
            u.y = (unsigned)f2bf(fmaxf(c[2], 0.0f)) | ((unsigned)f2bf(fmaxf(c[3], 0.0f)) << 16);
            *(uint2*)((char*)hs + l15 * 144 + 32 * ft + 8 * g) = u;
        }
        s8v hB0 = *(const s8v*)((const char*)hs + l15 * 144 + 16 * g);
        s8v hB1 = *(const s8v*)((const char*)hs + l15 * 144 + 64 + 16 * g);
        #pragma unroll
        for (int ct = 0; ct < 3; ++ct) {
            f4v p; p[0] = 0.0f; p[1] = 0.0f; p[2] = 0.0f; p[3] = 0.0f;
            f4v qv;
            qv[0] = b2v[ct][0]; qv[1] = b2v[ct][1]; qv[2] = b2v[ct][2]; qv[3] = b2v[ct][3];
            const size_t rb = (size_t)(16 * ct + l15) * 144 + 16 * g;
            s8v L0 = *(const s8v*)((const char*)wl2 + rb);
            s8v L1 = *(const s8v*)((const char*)wl2 + rb + 64);
            s8v Q0 = *(const s8v*)((const char*)wr2 + rb);
            s8v Q1 = *(const s8v*)((const char*)wr2 + rb + 64);
            p  = __builtin_amdgcn_mfma_f32_16x16x32_bf16(L0, hB0, p, 0, 0, 0);
            p  = __builtin_amdgcn_mfma_f32_16x16x32_bf16(L1, hB1, p, 0, 0, 0);
            qv = __builtin_amdgcn_mfma_f32_16x16x32_bf16(Q0, hB0, qv, 0, 0, 0);
            qv = __builtin_amdgcn_mfma_f32_16x16x32_bf16(Q1, hB1, qv, 0, 0, 0);
            int c0 = 16 * ct + 4 * g;
            // word 4*ct+g in 0..11; rows >= NCLS are zeros (zero-padded W2/b2)
            h2f8[node * 16 + (4 * ct + g)] = pack4_fp8(p[0], p[1], p[2], p[3]);
            if (c0 < NCLS) {
                float4 o; o.x = qv[0]; o.y = qv[1]; o.z = qv[2]; o.w = qv[3];
                *(float4*)&op[node * NCLS + c0] = o;
            }
        }
    }
}

// ---------------- layer-2 gather: out = mean(fp8 h2[src]) + op --------------
// h2 64B rows (one line/edge). Wave = 4 nodes x 4 chains x 4 lanes; lanes
// t=0..2 each load one uint4 (classes 16t..16t+15); packed fp8 accumulate.
__global__ __launch_bounds__(256) void k_out(
        const uint2* __restrict__ offdeg, const int* __restrict__ srcs,
        const unsigned int* __restrict__ h2f8, float* __restrict__ out) {
    const int lane = threadIdx.x & 63;
    const int w = threadIdx.x >> 6;
    const int g = lane >> 4;                   // node subgroup 0..3
    const int q = (lane >> 2) & 3;             // chain 0..3
    const int t = lane & 3;                    // uint4 word-group 0..3 (t<3 active)
    const int wid = blockIdx.x * 4 + w;        // 0..8191
    for (int nb = wid * 4; nb < N_NODES; nb += 32768) {
        const int node = nb + g;               // N_NODES % 4 == 0 -> in range
        uint2 od = offdeg[node];
        const int beg = (int)od.x;
        const int m = ((int)od.y + 3) >> 2;
        f2v a2[8];
        #pragma unroll
        for (int k = 0; k < 8; ++k) { a2[k].x = 0.0f; a2[k].y = 0.0f; }
        if (t < 3) {
            int j = q;
            if (j < m) {
                int4 sv = *(const int4*)&srcs[beg + 4 * j];
                while (true) {
                    const int4 cur = sv;
                    const int jn = j + 4;
                    if (jn < m) sv = *(const int4*)&srcs[beg + 4 * jn];   // prefetch
                    uint4 u0 = *(const uint4*)&h2f8[(size_t)cur.x * 16 + t * 4];
                    uint4 u1 = *(const uint4*)&h2f8[(size_t)cur.y * 16 + t * 4];
                    uint4 u2 = *(const uint4*)&h2f8[(size_t)cur.z * 16 + t * 4];
                    uint4 u3 = *(const uint4*)&h2f8[(size_t)cur.w * 16 + t * 4];
                    acc_fp8x16(u0, a2); acc_fp8x16(u1, a2);
                    acc_fp8x16(u2, a2); acc_fp8x16(u3, a2);
                    if (jn >= m) break;
                    j = jn;
                }
            }
        }
        float* a = (float*)a2;
        // reduce across chains (lane bits 2,3); stays inside 16-lane node group
        #pragma unroll
        for (int k = 0; k < 16; ++k) {
            a[k] += __shfl_xor(a[k], 4, 64);
            a[k] += __shfl_xor(a[k], 8, 64);
        }
        if (q == 0 && t < 3) {
            float rd = 1.0f / fmaxf((float)od.y, 1.0f);
            const int base = t * 16;
            const int nwords = (t == 2) ? 2 : 4;          // t==2: classes 32..39
            #pragma unroll
            for (int i = 0; i < 4; ++i) {
                if (i < nwords) {
                    float4 o = *(float4*)&out[(size_t)node * NCLS + base + 4 * i];
                    o.x = fmaf(a[4 * i + 0], rd, o.x);
                    o.y = fmaf(a[4 * i + 1], rd, o.y);
                    o.z = fmaf(a[4 * i + 2], rd, o.z);
                    o.w = fmaf(a[4 * i + 3], rd, o.w);
                    *(float4*)&out[(size_t)node * NCLS + base + 4 * i] = o;
                }
            }
        }
    }
}

extern "C" void kernel_launch(void* const* d_in, const int* in_sizes, int n_in,
                              void* d_out, int out_size, void* d_ws, size_t ws_size,
                              hipStream_t stream) {
    const float* x   = (const float*)d_in[0];
    const int*   ei  = (const int*)d_in[1];   // [2, E] int32
    const float* W1l = (const float*)d_in[2];
    const float* b1  = (const float*)d_in[3];
    const float* W1r = (const float*)d_in[4];
    const float* W2l = (const float*)d_in[5];
    const float* b2  = (const float*)d_in[6];
    const float* W2r = (const float*)d_in[7];
    float* out = (float*)d_out;

    const int* srcv = ei;
    const int* dstv = ei + N_EDGES;

    // ws: deg N | cur N | gcnt 1 | pad 1 | offdeg 2N | srcs E+3N+16 (padded CSR)
    //     | aggs 4*NN1*16 u16 (slice-major) | xbs 4*NN1*16 u16 (slice-major)
    //     | h2f8 16*NN1 u32 (64B rows) | xf8 16*NN1 u32 (fp8 x, 64B rows)
    int* deg    = (int*)d_ws;              // N ints
    int* cur    = deg + N_NODES;           // N ints
    int* gcnt   = cur + N_NODES;           // 1 int
    uint2* offdeg = (uint2*)(deg + 2 * N_NODES + 2);
    int* srcs   = (int*)(offdeg + N_NODES);
    unsigned short* aggs = (unsigned short*)(srcs + (size_t)N_EDGES + 3 * N_NODES + 16);
    unsigned short* xbs  = aggs + (size_t)64 * NN1;
    unsigned int*   h2f8 = (unsigned int*)(xbs + (size_t)64 * NN1);
    unsigned int*   xf8  = h2f8 + (size_t)16 * NN1;

    hipMemsetAsync(deg, 0, (2 * N_NODES + 2) * sizeof(int), stream);  // deg+cur+gcnt
    k_degxb<<<2048, 256, 0, stream>>>(dstv, x, deg, (unsigned int*)xbs, h2f8, xf8);
    k_scan<<<NBIN, 256, 0, stream>>>(deg, gcnt, offdeg, cur, srcs);
    k_scatter<<<2048, 256, 0, stream>>>(srcv, dstv, cur, srcs);
    k_agg<<<2048, 256, 0, stream>>>(offdeg, srcs, xf8, aggs);
    k_dense<<<768, 256, 0, stream>>>(aggs, xbs, W1l, b1, W1r, W2l, b2, W2r, h2f8, out);
    k_out<<<2048, 256, 0, stream>>>(offdeg, srcs, h2f8, out);
}

// Round 9
// 121.932 us; speedup vs baseline: 2.4034x; 2.4034x over previous
//
#include <hip/hip_runtime.h>

#define N_NODES 100000
#define N_EDGES 1600000
#define NCLS 40
#define BIN_SH 8
#define BIN_N 256                      // nodes per bin == block size
#define NBIN ((N_NODES + BIN_N - 1) / BIN_N)   // 391
#define BINCAP 4800                    // per-bin capacity (mean 4092 + ~11 sigma)
#define BKBLK 256                      // k_bucket blocks (1 per CU)
#define BKTHR 1024                     // k_bucket threads (16 waves/CU)
#define CHUNK (N_EDGES / BKBLK)        // 6250 edges per block
#define SENTINEL N_NODES               // pad index -> all-zero feature row
#define NN1 (N_NODES + 1)              // rows incl. sentinel

typedef __attribute__((ext_vector_type(8))) short s8v;   // 8 bf16 (4 VGPRs)
typedef __attribute__((ext_vector_type(4))) float f4v;   // MFMA C/D
typedef __attribute__((ext_vector_type(2))) float f2v;   // packed f32 pair

__device__ __forceinline__ unsigned short f2bf(float f) {
    union { float f; unsigned int u; } v; v.f = f;
    unsigned int u = v.u + 0x7FFFu + ((v.u >> 16) & 1u);   // RNE
    return (unsigned short)(u >> 16);
}
__device__ __forceinline__ float blo(unsigned int u) {
    union { unsigned int u; float f; } v; v.u = u << 16; return v.f;
}
__device__ __forceinline__ float bhi(unsigned int u) {
    union { unsigned int u; float f; } v; v.u = u & 0xFFFF0000u; return v.f;
}

// ---------------- fp8 e4m3 encode/decode (HW builtins, soft fallback) -------
#if __has_builtin(__builtin_amdgcn_cvt_pk_fp8_f32) && __has_builtin(__builtin_amdgcn_cvt_f32_fp8)
#define FP8_HW 1
#else
#define FP8_HW 0
#endif
#if __has_builtin(__builtin_amdgcn_cvt_pk_f32_fp8)
#define FP8_PK 1
#else
#define FP8_PK 0
#endif

__device__ __forceinline__ unsigned char enc_e4m3_sw(float f) {
    union { float f; unsigned int u; } v; v.f = f;
    unsigned int s = (v.u >> 24) & 0x80u;
    float af = fabsf(f);
    if (af >= 448.0f) return (unsigned char)(s | 0x7E);
    if (af < 0.015625f) {
        int q = (int)rintf(af * 512.0f);
        return (unsigned char)(s | (q & 7));
    }
    unsigned int n = v.u & 0x7FFFFFFFu;
    n = n + 0x7FFFFu + ((n >> 20) & 1u);
    int e = (int)(n >> 23) - 120;
    unsigned int m = (n >> 20) & 7u;
    if (e <= 0) { int q = (int)rintf(af * 512.0f); return (unsigned char)(s | (q & 7)); }
    if (e > 15) return (unsigned char)(s | 0x7E);
    return (unsigned char)(s | (e << 3) | m);
}
__device__ __forceinline__ float dec_e4m3_sw(unsigned int byte) {
    unsigned int sgn = byte >> 7, e = (byte >> 3) & 15u, m = byte & 7u;
    float mag;
    if (e) { union { unsigned int u; float f; } v; v.u = ((e + 120u) << 23) | (m << 20); mag = v.f; }
    else mag = (float)m * 0.001953125f;
    return sgn ? -mag : mag;
}

__device__ __forceinline__ unsigned int pack4_fp8(float a, float b, float c, float d) {
#if FP8_HW
    unsigned int w = __builtin_amdgcn_cvt_pk_fp8_f32(a, b, 0u, false);
    w = __builtin_amdgcn_cvt_pk_fp8_f32(c, d, w, true);
    return w;
#else
    return (unsigned int)enc_e4m3_sw(a) | ((unsigned int)enc_e4m3_sw(b) << 8) |
           ((unsigned int)enc_e4m3_sw(c) << 16) | ((unsigned int)enc_e4m3_sw(d) << 24);
#endif
}

// packed accumulate: 4 fp8 of word w into two f2v accumulators (a[0],a[1])
__device__ __forceinline__ void acc_fp8pk(unsigned int w, f2v* a) {
#if FP8_PK
    a[0] += __builtin_amdgcn_cvt_pk_f32_fp8((int)w, false);   // bytes 0,1
    a[1] += __builtin_amdgcn_cvt_pk_f32_fp8((int)w, true);    // bytes 2,3
#else
    f2v lo, hi;
    lo.x = dec_e4m3_sw(w & 255u);         lo.y = dec_e4m3_sw((w >> 8) & 255u);
    hi.x = dec_e4m3_sw((w >> 16) & 255u); hi.y = dec_e4m3_sw(w >> 24);
    a[0] += lo; a[1] += hi;
#endif
}
// accumulate 16 fp8 of a uint4 into a[0..7] (f2v pairs, 16 floats total)
__device__ __forceinline__ void acc_fp8x16(uint4 u, f2v* a) {
    acc_fp8pk(u.x, a + 0); acc_fp8pk(u.y, a + 2);
    acc_fp8pk(u.z, a + 4); acc_fp8pk(u.w, a + 6);
}

// ---------------- bucketing into 391 x 256-node bins + x conversions --------
// R8 lesson: direct scatter = 105MB line-RMW writes + global atomic latency.
// Bucketed build keeps atomic returns in LDS and writes bin-private regions.
// x->bf16 (slice-major) and x->fp8 conversions fused here: independent
// streaming work that fills the LDS-atomic passes' latency gaps.
__global__ __launch_bounds__(BKTHR) void k_bucket(
        const int* __restrict__ srcv, const int* __restrict__ dstv,
        int* __restrict__ bcur, int* __restrict__ bedges,
        const float* __restrict__ x, unsigned int* __restrict__ xbs,
        unsigned int* __restrict__ h2f8, unsigned int* __restrict__ xf8) {
    __shared__ int cnt4[4][NBIN];
    __shared__ int base[NBIN], lcur[NBIN];
    for (int i = threadIdx.x; i < 4 * NBIN; i += BKTHR) cnt4[i / NBIN][i % NBIN] = 0;
    __syncthreads();
    const int gid = blockIdx.x * BKTHR + threadIdx.x;
    const int gstride = BKBLK * BKTHR;
    // ---- fused conversions (no sync dependency on bucketing) ----
    const int total = N_NODES * 8;             // 16B tiles (8 f32 -> 8 bf16)
    for (int tt = gid; tt < total; tt += gstride) {
        int node = tt >> 3, sub = tt & 7;      // feats sub*8 .. sub*8+7
        int slice = sub >> 1, half = sub & 1;
        float4 v0 = ((const float4*)x)[tt * 2];
        float4 v1 = ((const float4*)x)[tt * 2 + 1];
        uint4 o;
        o.x = (unsigned)f2bf(v0.x) | ((unsigned)f2bf(v0.y) << 16);
        o.y = (unsigned)f2bf(v0.z) | ((unsigned)f2bf(v0.w) << 16);
        o.z = (unsigned)f2bf(v1.x) | ((unsigned)f2bf(v1.y) << 16);
        o.w = (unsigned)f2bf(v1.z) | ((unsigned)f2bf(v1.w) << 16);
        ((uint4*)xbs)[((size_t)slice * NN1 + node) * 2 + half] = o;
        uint2 p;
        p.x = pack4_fp8(v0.x, v0.y, v0.z, v0.w);
        p.y = pack4_fp8(v1.x, v1.y, v1.z, v1.w);
        ((uint2*)xf8)[(size_t)node * 8 + sub] = p;
    }
    // zero sentinel rows: 4 xbs slices; h2 words 0..11; xf8 row (16 u32)
    uint4 z; z.x = 0u; z.y = 0u; z.z = 0u; z.w = 0u;
    if (gid < 8) {
        int slice = gid >> 1, half = gid & 1;
        ((uint4*)xbs)[((size_t)slice * NN1 + N_NODES) * 2 + half] = z;
    }
    if (gid >= 16 && gid < 28) h2f8[(size_t)N_NODES * 16 + (gid - 16)] = 0u;
    if (gid >= 32 && gid < 48) xf8[(size_t)N_NODES * 16 + (gid - 32)] = 0u;
    // ---- bucketing ----
    const int grp = threadIdx.x >> 8;
    const int beg = blockIdx.x * CHUNK;
    const int end = beg + CHUNK;
    for (int e = beg + threadIdx.x; e < end; e += BKTHR) {
        int d = dstv[e]; d = min(max(d, 0), N_NODES - 1);
        atomicAdd(&cnt4[grp][d >> BIN_SH], 1);
    }
    __syncthreads();
    for (int i = threadIdx.x; i < NBIN; i += BKTHR) {
        int c = cnt4[0][i] + cnt4[1][i] + cnt4[2][i] + cnt4[3][i];
        base[i] = atomicAdd(&bcur[i], c);
        lcur[i] = 0;
    }
    __syncthreads();
    for (int e = beg + threadIdx.x; e < end; e += BKTHR) {
        int d = dstv[e]; d = min(max(d, 0), N_NODES - 1);
        int s = srcv[e]; s = min(max(s, 0), N_NODES - 1);
        int b = d >> BIN_SH;
        int slot = atomicAdd(&lcur[b], 1) + base[b];
        if (slot < BINCAP) bedges[b * BINCAP + slot] = ((d & (BIN_N - 1)) << 17) | s;
    }
}

// ---------------- fused CSR: histogram + scan + base-claim + fill -----------
// Regions padded to multiples of 4 slots; pads hold SENTINEL (zero row).
__global__ __launch_bounds__(256) void k_csrfill(
        const int* __restrict__ bcur, const int* __restrict__ bedges,
        int* __restrict__ gcnt, uint2* __restrict__ offdeg,
        int* __restrict__ srcs) {
    __shared__ int dcnt[BIN_N];
    __shared__ int s[BIN_N];
    __shared__ int base_s;
    const int b = blockIdx.x;
    dcnt[threadIdx.x] = 0;
    __syncthreads();
    const int cnt = min(bcur[b], BINCAP);
    for (int e = threadIdx.x; e < cnt; e += 256)
        atomicAdd(&dcnt[bedges[b * BINCAP + e] >> 17], 1);
    __syncthreads();
    int v = dcnt[threadIdx.x];
    int pv = (v + 3) & ~3;                 // padded degree (multiple of 4)
    s[threadIdx.x] = pv;
    __syncthreads();
    int acc = pv;
    for (int off = 1; off < 256; off <<= 1) {
        int t = (threadIdx.x >= off) ? s[threadIdx.x - off] : 0;
        __syncthreads();
        acc += t;
        s[threadIdx.x] = acc;
        __syncthreads();
    }
    if (threadIdx.x == 255) base_s = atomicAdd(gcnt, acc);
    __syncthreads();
    const int gbeg = (acc - pv) + base_s;  // multiple of 4 -> 16B-aligned
    const int node = (b << BIN_SH) + threadIdx.x;
    if (node < N_NODES) offdeg[node] = make_uint2((unsigned)gbeg, (unsigned)v);
    s[threadIdx.x] = gbeg;
    dcnt[threadIdx.x] = 0;
    __syncthreads();
    for (int e = threadIdx.x; e < cnt; e += 256) {
        int val = bedges[b * BINCAP + e];
        int dl = val >> 17;
        int sv = val & 0x1FFFF;
        int slot = atomicAdd(&dcnt[dl], 1);
        srcs[s[dl] + slot] = sv;
    }
    for (int p = v; p < pv; ++p) srcs[gbeg + p] = SENTINEL;
}

// ---------------- gather-mean over fp8 rows (64B = 1 line/edge) -------------
// xf8 row = 64 feats fp8 = one cache line; 4 adjacent lanes x uint4 coalesce
// to ONE line-request per edge (validated R7). Wave = 4 nodes x 4 chains x
// 4 lanes; chain walks int4 blocks with prefetch.
__global__ __launch_bounds__(256) void k_agg(
        const uint2* __restrict__ offdeg, const int* __restrict__ srcs,
        const unsigned int* __restrict__ xf8, unsigned short* __restrict__ aggs) {
    const int lane = threadIdx.x & 63;
    const int w = threadIdx.x >> 6;            // wave 0..3
    const int g = lane >> 4;                   // node subgroup 0..3
    const int c = (lane >> 2) & 3;             // chain 0..3
    const int t = lane & 3;                    // 16B quarter of 64B row
    const int wid = blockIdx.x * 4 + w;        // 0..8191
    for (int nb = wid * 4; nb < N_NODES; nb += 32768) {
        const int node = nb + g;               // N_NODES % 4 == 0 -> in range
        uint2 od = offdeg[node];
        const int beg = (int)od.x;
        const int m = ((int)od.y + 3) >> 2;
        f2v a2[8];
        #pragma unroll
        for (int k = 0; k < 8; ++k) { a2[k].x = 0.0f; a2[k].y = 0.0f; }
        int j = c;
        if (j < m) {
            int4 sv = *(const int4*)&srcs[beg + 4 * j];
            while (true) {
                const int4 cur = sv;
                const int jn = j + 4;
                if (jn < m) sv = *(const int4*)&srcs[beg + 4 * jn];   // prefetch
                uint4 u0 = *(const uint4*)&xf8[(size_t)cur.x * 16 + t * 4];
                uint4 u1 = *(const uint4*)&xf8[(size_t)cur.y * 16 + t * 4];
                uint4 u2 = *(const uint4*)&xf8[(size_t)cur.z * 16 + t * 4];
                uint4 u3 = *(const uint4*)&xf8[(size_t)cur.w * 16 + t * 4];
                acc_fp8x16(u0, a2); acc_fp8x16(u1, a2);
                acc_fp8x16(u2, a2); acc_fp8x16(u3, a2);
                if (jn >= m) break;
                j = jn;
            }
        }
        float* af = (float*)a2;
        // reduce across chains (lane bits 2,3); stays inside 16-lane node group
        #pragma unroll
        for (int k = 0; k < 16; ++k) {
            af[k] += __shfl_xor(af[k], 4, 64);
            af[k] += __shfl_xor(af[k], 8, 64);
        }
        if (c == 0) {
            // lane t holds feats 16t..16t+15 == slice t's 32B row (slice-major)
            float rd = 1.0f / fmaxf((float)od.y, 1.0f);
            uint4 r0, r1;
            r0.x = (unsigned)f2bf(af[0] * rd)  | ((unsigned)f2bf(af[1] * rd) << 16);
            r0.y = (unsigned)f2bf(af[2] * rd)  | ((unsigned)f2bf(af[3] * rd) << 16);
            r0.z = (unsigned)f2bf(af[4] * rd)  | ((unsigned)f2bf(af[5] * rd) << 16);
            r0.w = (unsigned)f2bf(af[6] * rd)  | ((unsigned)f2bf(af[7] * rd) << 16);
            r1.x = (unsigned)f2bf(af[8] * rd)  | ((unsigned)f2bf(af[9] * rd) << 16);
            r1.y = (unsigned)f2bf(af[10] * rd) | ((unsigned)f2bf(af[11] * rd) << 16);
            r1.z = (unsigned)f2bf(af[12] * rd) | ((unsigned)f2bf(af[13] * rd) << 16);
            r1.w = (unsigned)f2bf(af[14] * rd) | ((unsigned)f2bf(af[15] * rd) << 16);
            unsigned short* dst = &aggs[((size_t)t * NN1 + node) * 16];
            *(uint4*)dst = r0;
            *(uint4*)(dst + 8) = r1;
        }
    }
}

// ---------------- fused dense via MFMA; h2 fp8, 64B rows, words 0..11 -------
__global__ __launch_bounds__(256) void k_dense(
        const unsigned short* __restrict__ aggs, const unsigned short* __restrict__ xbs,
        const float* __restrict__ W1l, const float* __restrict__ b1,
        const float* __restrict__ W1r,
        const float* __restrict__ W2l, const float* __restrict__ b2,
        const float* __restrict__ W2r,
        unsigned int* __restrict__ h2f8, float* __restrict__ op) {
    __shared__ __align__(16) unsigned short wl1[64][72], wr1[64][72];
    __shared__ __align__(16) unsigned short wl2[48][72], wr2[48][72];
    __shared__ __align__(16) unsigned short hsm[4][16][72];
    for (int idx = threadIdx.x; idx < 64 * 64; idx += 256) {
        int f = idx >> 6, k = idx & 63;
        wl1[f][k] = f2bf(W1l[idx]);
        wr1[f][k] = f2bf(W1r[idx]);
    }
    for (int idx = threadIdx.x; idx < 48 * 64; idx += 256) {
        int c = idx >> 6, k = idx & 63;
        wl2[c][k] = (c < NCLS) ? f2bf(W2l[c * 64 + k]) : (unsigned short)0;
        wr2[c][k] = (c < NCLS) ? f2bf(W2r[c * 64 + k]) : (unsigned short)0;
    }
    __syncthreads();
    const int w   = threadIdx.x >> 6;
    const int l15 = threadIdx.x & 15;
    const int g   = (threadIdx.x >> 4) & 3;
    const size_t sLo = (size_t)(g >> 1) * NN1;        // feats 0..31 source
    const size_t sHi = (size_t)(2 + (g >> 1)) * NN1;  // feats 32..63 source
    const int off = (g & 1) * 8;
    float b1v[4][4], b2v[3][4];
    #pragma unroll
    for (int ft = 0; ft < 4; ++ft)
        #pragma unroll
        for (int r = 0; r < 4; ++r)
            b1v[ft][r] = b1[16 * ft + 4 * g + r];
    #pragma unroll
    for (int ct = 0; ct < 3; ++ct)
        #pragma unroll
        for (int r = 0; r < 4; ++r) {
            int c = 16 * ct + 4 * g + r;
            b2v[ct][r] = (c < NCLS) ? b2[c] : 0.0f;
        }
    unsigned short* hs = &hsm[w][0][0];
    const int gw = blockIdx.x * 4 + w;
    const int nw = gridDim.x * 4;
    for (int tile = gw; tile < N_NODES / 16; tile += nw) {
        const size_t node = (size_t)tile * 16 + l15;
        s8v aB0 = *(const s8v*)&aggs[(sLo + node) * 16 + off];
        s8v aB1 = *(const s8v*)&aggs[(sHi + node) * 16 + off];
        s8v xB0 = *(const s8v*)&xbs[(sLo + node) * 16 + off];
        s8v xB1 = *(const s8v*)&xbs[(sHi + node) * 16 + off];
        #pragma unroll
        for (int ft = 0; ft < 4; ++ft) {
            f4v c;
            c[0] = b1v[ft][0]; c[1] = b1v[ft][1]; c[2] = b1v[ft][2]; c[3] = b1v[ft][3];
            const size_t rb = (size_t)(16 * ft + l15) * 144 + 16 * g;
            s8v A0 = *(const s8v*)((const char*)wl1 + rb);
            s8v A1 = *(const s8v*)((const char*)wl1 + rb + 64);
            s8v R0 = *(const s8v*)((const char*)wr1 + rb);
            s8v R1 = *(const s8v*)((const char*)wr1 + rb + 64);
            c = __builtin_amdgcn_mfma_f32_16x16x32_bf16(A0, aB0, c, 0, 0, 0);
            c = __builtin_amdgcn_mfma_f32_16x16x32_bf16(A1, aB1, c, 0, 0, 0);
            c = __builtin_amdgcn_mfma_f32_16x16x32_bf16(R0, xB0, c, 0, 0, 0);
            c = __builtin_amdgcn_mfma_f32_16x16x32_bf16(R1, xB1, c, 0, 0, 0);
            uint2 u;
            u.x = (unsigned)f2bf(fmaxf(c[0], 0.0f)) | ((unsigned)f2bf(fmaxf(c[1], 0.0f)) << 16);
            u.y = (unsigned)f2bf(fmaxf(c[2], 0.0f)) | ((unsigned)f2bf(fmaxf(c[3], 0.0f)) << 16);
            *(uint2*)((char*)hs + l15 * 144 + 32 * ft + 8 * g) = u;
        }
        s8v hB0 = *(const s8v*)((const char*)hs + l15 * 144 + 16 * g);
        s8v hB1 = *(const s8v*)((const char*)hs + l15 * 144 + 64 + 16 * g);
        #pragma unroll
        for (int ct = 0; ct < 3; ++ct) {
            f4v p; p[0] = 0.0f; p[1] = 0.0f; p[2] = 0.0f; p[3] = 0.0f;
            f4v qv;
            qv[0] = b2v[ct][0]; qv[1] = b2v[ct][1]; qv[2] = b2v[ct][2]; qv[3] = b2v[ct][3];
            const size_t rb = (size_t)(16 * ct + l15) * 144 + 16 * g;
            s8v L0 = *(const s8v*)((const char*)wl2 + rb);
            s8v L1 = *(const s8v*)((const char*)wl2 + rb + 64);
            s8v Q0 = *(const s8v*)((const char*)wr2 + rb);
            s8v Q1 = *(const s8v*)((const char*)wr2 + rb + 64);
            p  = __builtin_amdgcn_mfma_f32_16x16x32_bf16(L0, hB0, p, 0, 0, 0);
            p  = __builtin_amdgcn_mfma_f32_16x16x32_bf16(L1, hB1, p, 0, 0, 0);
            qv = __builtin_amdgcn_mfma_f32_16x16x32_bf16(Q0, hB0, qv, 0, 0, 0);
            qv = __builtin_amdgcn_mfma_f32_16x16x32_bf16(Q1, hB1, qv, 0, 0, 0);
            int c0 = 16 * ct + 4 * g;
            // word 4*ct+g in 0..11; rows >= NCLS are zeros (zero-padded W2/b2)
            h2f8[node * 16 + (4 * ct + g)] = pack4_fp8(p[0], p[1], p[2], p[3]);
            if (c0 < NCLS) {
                float4 o; o.x = qv[0]; o.y = qv[1]; o.z = qv[2]; o.w = qv[3];
                *(float4*)&op[node * NCLS + c0] = o;
            }
        }
    }
}

// ---------------- layer-2 gather: out = mean(fp8 h2[src]) + op --------------
// h2 64B rows (one line/edge). Wave = 4 nodes x 4 chains x 4 lanes; lanes
// t=0..2 each load one uint4 (classes 16t..16t+15); packed fp8 accumulate.
__global__ __launch_bounds__(256) void k_out(
        const uint2* __restrict__ offdeg, const int* __restrict__ srcs,
        const unsigned int* __restrict__ h2f8, float* __restrict__ out) {
    const int lane = threadIdx.x & 63;
    const int w = threadIdx.x >> 6;
    const int g = lane >> 4;                   // node subgroup 0..3
    const int q = (lane >> 2) & 3;             // chain 0..3
    const int t = lane & 3;                    // uint4 word-group 0..3 (t<3 active)
    const int wid = blockIdx.x * 4 + w;        // 0..8191
    for (int nb = wid * 4; nb < N_NODES; nb += 32768) {
        const int node = nb + g;               // N_NODES % 4 == 0 -> in range
        uint2 od = offdeg[node];
        const int beg = (int)od.x;
        const int m = ((int)od.y + 3) >> 2;
        f2v a2[8];
        #pragma unroll
        for (int k = 0; k < 8; ++k) { a2[k].x = 0.0f; a2[k].y = 0.0f; }
        if (t < 3) {
            int j = q;
            if (j < m) {
                int4 sv = *(const int4*)&srcs[beg + 4 * j];
                while (true) {
                    const int4 cur = sv;
                    const int jn = j + 4;
                    if (jn < m) sv = *(const int4*)&srcs[beg + 4 * jn];   // prefetch
                    uint4 u0 = *(const uint4*)&h2f8[(size_t)cur.x * 16 + t * 4];
                    uint4 u1 = *(const uint4*)&h2f8[(size_t)cur.y * 16 + t * 4];
                    uint4 u2 = *(const uint4*)&h2f8[(size_t)cur.z * 16 + t * 4];
                    uint4 u3 = *(const uint4*)&h2f8[(size_t)cur.w * 16 + t * 4];
                    acc_fp8x16(u0, a2); acc_fp8x16(u1, a2);
                    acc_fp8x16(u2, a2); acc_fp8x16(u3, a2);
                    if (jn >= m) break;
                    j = jn;
                }
            }
        }
        float* a = (float*)a2;
        // reduce across chains (lane bits 2,3); stays inside 16-lane node group
        #pragma unroll
        for (int k = 0; k < 16; ++k) {
            a[k] += __shfl_xor(a[k], 4, 64);
            a[k] += __shfl_xor(a[k], 8, 64);
        }
        if (q == 0 && t < 3) {
            float rd = 1.0f / fmaxf((float)od.y, 1.0f);
            const int base = t * 16;
            const int nwords = (t == 2) ? 2 : 4;          // t==2: classes 32..39
            #pragma unroll
            for (int i = 0; i < 4; ++i) {
                if (i < nwords) {
                    float4 o = *(float4*)&out[(size_t)node * NCLS + base + 4 * i];
                    o.x = fmaf(a[4 * i + 0], rd, o.x);
                    o.y = fmaf(a[4 * i + 1], rd, o.y);
                    o.z = fmaf(a[4 * i + 2], rd, o.z);
                    o.w = fmaf(a[4 * i + 3], rd, o.w);
                    *(float4*)&out[(size_t)node * NCLS + base + 4 * i] = o;
                }
            }
        }
    }
}

extern "C" void kernel_launch(void* const* d_in, const int* in_sizes, int n_in,
                              void* d_out, int out_size, void* d_ws, size_t ws_size,
                              hipStream_t stream) {
    const float* x   = (const float*)d_in[0];
    const int*   ei  = (const int*)d_in[1];   // [2, E] int32
    const float* W1l = (const float*)d_in[2];
    const float* b1  = (const float*)d_in[3];
    const float* W1r = (const float*)d_in[4];
    const float* W2l = (const float*)d_in[5];
    const float* b2  = (const float*)d_in[6];
    const float* W2r = (const float*)d_in[7];
    float* out = (float*)d_out;

    const int* srcv = ei;
    const int* dstv = ei + N_EDGES;

    // ws: bcur 508 | gcnt 1 | offdeg 2N | bedges NBIN*BINCAP
    //     | srcs E+3N+16 (padded CSR) | aggs 4*NN1*16 u16 (slice-major)
    //     | xbs 4*NN1*16 u16 (slice-major) | h2f8 16*NN1 u32 (64B rows)
    //     | xf8 16*NN1 u32 (fp8 x, 64B rows)
    int* bcur   = (int*)d_ws;              // 508 ints for bins
    int* gcnt   = bcur + 508;              // 1 int (zeroed with bcur)
    uint2* offdeg = (uint2*)(bcur + 512);
    int* bedges = (int*)(offdeg + N_NODES);
    int* srcs   = bedges + (size_t)NBIN * BINCAP;
    unsigned short* aggs = (unsigned short*)(srcs + (size_t)N_EDGES + 3 * N_NODES + 16);
    unsigned short* xbs  = aggs + (size_t)64 * NN1;
    unsigned int*   h2f8 = (unsigned int*)(xbs + (size_t)64 * NN1);
    unsigned int*   xf8  = h2f8 + (size_t)16 * NN1;

    hipMemsetAsync(bcur, 0, 512 * sizeof(int), stream);
    k_bucket<<<BKBLK, BKTHR, 0, stream>>>(srcv, dstv, bcur, bedges,
                                          x, (unsigned int*)xbs, h2f8, xf8);
    k_csrfill<<<NBIN, 256, 0, stream>>>(bcur, bedges, gcnt, offdeg, srcs);
    k_agg<<<2048, 256, 0, stream>>>(offdeg, srcs, xf8, aggs);
    k_dense<<<768, 256, 0, stream>>>(aggs, xbs, W1l, b1, W1r, W2l, b2, W2r, h2f8, out);
    k_out<<<2048, 256, 0, stream>>>(offdeg, srcs, h2f8, out);
}